// Round 1
// baseline (328.382 us; speedup 1.0000x reference)
//
#include <hip/hip_runtime.h>
#include <hip/hip_bf16.h>
#include <math.h>

// Problem constants from the reference: B=64, H=192, W=192, STRIDE=8, EPS=1e-7
#define STRIDE_F 8.0f
#define EPS_F 1e-7f

__global__ __launch_bounds__(256) void ciou_loss_kernel(
    const float* __restrict__ pred, const float* __restrict__ tgt,
    const int* __restrict__ mask, float* __restrict__ acc,
    int total, int HW, int W)
{
    int idx = blockIdx.x * blockDim.x + threadIdx.x;
    float ls = 0.0f;  // sum of (1 - ciou) * m
    float ms = 0.0f;  // sum of m
    if (idx < total) {
        int bb = idx / HW;
        int hw = idx - bb * HW;
        int h  = hw / W;
        int w  = hw - h * W;

        float cx = ((float)w + 0.5f) * STRIDE_F;
        float cy = ((float)h + 0.5f) * STRIDE_F;

        size_t base = (size_t)bb * 4 * (size_t)HW + (size_t)hw;
        float pl = pred[base];
        float pt = pred[base + (size_t)HW];
        float pr = pred[base + 2 * (size_t)HW];
        float pb = pred[base + 3 * (size_t)HW];
        float tl = tgt[base];
        float tt = tgt[base + (size_t)HW];
        float tr = tgt[base + 2 * (size_t)HW];
        float tb = tgt[base + 3 * (size_t)HW];

        // decode_bbox
        float px1 = cx - pl * STRIDE_F;
        float py1 = cy - pt * STRIDE_F;
        float px2 = cx + pr * STRIDE_F;
        float py2 = cy + pb * STRIDE_F;
        float tx1 = cx - tl * STRIDE_F;
        float ty1 = cy - tt * STRIDE_F;
        float tx2 = cx + tr * STRIDE_F;
        float ty2 = cy + tb * STRIDE_F;

        // bbox_iou_ciou
        float w1 = px2 - px1, h1 = py2 - py1;
        float w2 = tx2 - tx1, h2 = ty2 - ty1;
        float iw = fminf(px2, tx2) - fmaxf(px1, tx1);
        float ih = fminf(py2, ty2) - fmaxf(py1, ty1);
        iw = fmaxf(iw, 0.0f);
        ih = fmaxf(ih, 0.0f);
        float inter = iw * ih;
        float uni   = w1 * h1 + w2 * h2 - inter + EPS_F;
        float iou   = inter / uni;

        float cw = fmaxf(px2, tx2) - fminf(px1, tx1);
        float ch = fmaxf(py2, ty2) - fminf(py1, ty1);
        float c2 = cw * cw + ch * ch + EPS_F;

        float dx = tx1 + tx2 - px1 - px2;
        float dy = ty1 + ty2 - py1 - py2;
        float rho2 = (dx * dx + dy * dy) * 0.25f;

        const float FOUR_OVER_PI2 = 0.40528473456935109f; // 4/pi^2
        float dv = atanf(w2 / (h2 + EPS_F)) - atanf(w1 / (h1 + EPS_F));
        float v  = FOUR_OVER_PI2 * dv * dv;
        float alpha = v / (v - iou + (1.0f + EPS_F));
        float ciou  = iou - rho2 / c2 - alpha * v;

        float m = (mask[idx] != 0) ? 1.0f : 0.0f;
        ls = (1.0f - ciou) * m;
        ms = m;
    }

    // wave-64 reduction
    #pragma unroll
    for (int off = 32; off > 0; off >>= 1) {
        ls += __shfl_down(ls, off, 64);
        ms += __shfl_down(ms, off, 64);
    }
    __shared__ float s_l[4];
    __shared__ float s_m[4];
    int wave = threadIdx.x >> 6;
    int lane = threadIdx.x & 63;
    if (lane == 0) { s_l[wave] = ls; s_m[wave] = ms; }
    __syncthreads();
    if (threadIdx.x == 0) {
        float tls = s_l[0] + s_l[1] + s_l[2] + s_l[3];
        float tms = s_m[0] + s_m[1] + s_m[2] + s_m[3];
        atomicAdd(&acc[0], tls);
        atomicAdd(&acc[1], tms);
    }
}

__global__ void finalize_kernel(const float* __restrict__ acc, float* __restrict__ out)
{
    out[0] = acc[0] / fmaxf(acc[1], 1.0f);
}

extern "C" void kernel_launch(void* const* d_in, const int* in_sizes, int n_in,
                              void* d_out, int out_size, void* d_ws, size_t ws_size,
                              hipStream_t stream) {
    const float* pred = (const float*)d_in[0];
    const float* tgt  = (const float*)d_in[1];
    const int*   mask = (const int*)d_in[2];   // bool mask uploaded as int32 per harness integer rule
    float* out = (float*)d_out;
    float* acc = (float*)d_ws;

    const int B = 64, H = 192, W = 192;
    const int HW = H * W;
    const int total = B * HW;   // == in_sizes[2]

    hipMemsetAsync(acc, 0, 2 * sizeof(float), stream);

    const int threads = 256;
    const int blocks = (total + threads - 1) / threads;
    ciou_loss_kernel<<<blocks, threads, 0, stream>>>(pred, tgt, mask, acc, total, HW, W);
    finalize_kernel<<<1, 1, 0, stream>>>(acc, out);
}

// Round 2
// 106.958 us; speedup vs baseline: 3.0702x; 3.0702x over previous
//
#include <hip/hip_runtime.h>
#include <hip/hip_bf16.h>
#include <math.h>

// Problem constants from the reference: B=64, H=192, W=192, STRIDE=8, EPS=1e-7
#define STRIDE_F 8.0f
#define EPS_F 1e-7f

// B*H*W = 2359296 elements; vec4 -> 589824 threads = 2304 blocks x 256.
// Each block writes one float2 partial (loss_sum, mask_sum) to d_ws.

__device__ __forceinline__ void ciou_elem(
    float cx, float cy,
    float pl, float pt, float pr, float pb,
    float tl, float tt, float tr, float tb,
    int m_i, float& ls, float& ms)
{
    float px1 = cx - pl * STRIDE_F;
    float py1 = cy - pt * STRIDE_F;
    float px2 = cx + pr * STRIDE_F;
    float py2 = cy + pb * STRIDE_F;
    float tx1 = cx - tl * STRIDE_F;
    float ty1 = cy - tt * STRIDE_F;
    float tx2 = cx + tr * STRIDE_F;
    float ty2 = cy + tb * STRIDE_F;

    float w1 = px2 - px1, h1 = py2 - py1;
    float w2 = tx2 - tx1, h2 = ty2 - ty1;
    float iw = fmaxf(fminf(px2, tx2) - fmaxf(px1, tx1), 0.0f);
    float ih = fmaxf(fminf(py2, ty2) - fmaxf(py1, ty1), 0.0f);
    float inter = iw * ih;
    float uni   = w1 * h1 + w2 * h2 - inter + EPS_F;
    float iou   = inter / uni;

    float cw = fmaxf(px2, tx2) - fminf(px1, tx1);
    float ch = fmaxf(py2, ty2) - fminf(py1, ty1);
    float c2 = cw * cw + ch * ch + EPS_F;

    float dx = tx1 + tx2 - px1 - px2;
    float dy = ty1 + ty2 - py1 - py2;
    float rho2 = (dx * dx + dy * dy) * 0.25f;

    const float FOUR_OVER_PI2 = 0.40528473456935109f; // 4/pi^2
    float dv = atanf(w2 / (h2 + EPS_F)) - atanf(w1 / (h1 + EPS_F));
    float v  = FOUR_OVER_PI2 * dv * dv;
    float alpha = v / (v - iou + (1.0f + EPS_F));
    float ciou  = iou - rho2 / c2 - alpha * v;

    float m = (m_i != 0) ? 1.0f : 0.0f;
    ls += (1.0f - ciou) * m;
    ms += m;
}

__global__ __launch_bounds__(256) void ciou_loss_kernel(
    const float4* __restrict__ pred, const float4* __restrict__ tgt,
    const int4* __restrict__ mask, float2* __restrict__ parts,
    int HW4, int W4)
{
    int idx4 = blockIdx.x * blockDim.x + threadIdx.x;
    // exact launch: grid*block == total/4, no bounds check needed
    int bb  = idx4 / HW4;
    int hw4 = idx4 - bb * HW4;
    int h   = hw4 / W4;
    int w4  = hw4 - h * W4;

    float cy = ((float)h + 0.5f) * STRIDE_F;
    float cx0 = ((float)(w4 * 4) + 0.5f) * STRIDE_F;

    size_t base = (size_t)bb * 4 * (size_t)HW4 + (size_t)hw4;
    float4 pl4 = pred[base];
    float4 pt4 = pred[base + (size_t)HW4];
    float4 pr4 = pred[base + 2 * (size_t)HW4];
    float4 pb4 = pred[base + 3 * (size_t)HW4];
    float4 tl4 = tgt[base];
    float4 tt4 = tgt[base + (size_t)HW4];
    float4 tr4 = tgt[base + 2 * (size_t)HW4];
    float4 tb4 = tgt[base + 3 * (size_t)HW4];
    int4   mk4 = mask[idx4];

    float ls = 0.0f, ms = 0.0f;
    ciou_elem(cx0 + 0.0f * STRIDE_F, cy, pl4.x, pt4.x, pr4.x, pb4.x,
              tl4.x, tt4.x, tr4.x, tb4.x, mk4.x, ls, ms);
    ciou_elem(cx0 + 1.0f * STRIDE_F, cy, pl4.y, pt4.y, pr4.y, pb4.y,
              tl4.y, tt4.y, tr4.y, tb4.y, mk4.y, ls, ms);
    ciou_elem(cx0 + 2.0f * STRIDE_F, cy, pl4.z, pt4.z, pr4.z, pb4.z,
              tl4.z, tt4.z, tr4.z, tb4.z, mk4.z, ls, ms);
    ciou_elem(cx0 + 3.0f * STRIDE_F, cy, pl4.w, pt4.w, pr4.w, pb4.w,
              tl4.w, tt4.w, tr4.w, tb4.w, mk4.w, ls, ms);

    // wave-64 reduction
    #pragma unroll
    for (int off = 32; off > 0; off >>= 1) {
        ls += __shfl_down(ls, off, 64);
        ms += __shfl_down(ms, off, 64);
    }
    __shared__ float s_l[4];
    __shared__ float s_m[4];
    int wave = threadIdx.x >> 6;
    int lane = threadIdx.x & 63;
    if (lane == 0) { s_l[wave] = ls; s_m[wave] = ms; }
    __syncthreads();
    if (threadIdx.x == 0) {
        float2 p;
        p.x = s_l[0] + s_l[1] + s_l[2] + s_l[3];
        p.y = s_m[0] + s_m[1] + s_m[2] + s_m[3];
        parts[blockIdx.x] = p;
    }
}

__global__ __launch_bounds__(256) void reduce_kernel(
    const float2* __restrict__ parts, int n, float* __restrict__ out)
{
    float ls = 0.0f, ms = 0.0f;
    for (int i = threadIdx.x; i < n; i += 256) {
        float2 p = parts[i];
        ls += p.x;
        ms += p.y;
    }
    #pragma unroll
    for (int off = 32; off > 0; off >>= 1) {
        ls += __shfl_down(ls, off, 64);
        ms += __shfl_down(ms, off, 64);
    }
    __shared__ float s_l[4];
    __shared__ float s_m[4];
    int wave = threadIdx.x >> 6;
    int lane = threadIdx.x & 63;
    if (lane == 0) { s_l[wave] = ls; s_m[wave] = ms; }
    __syncthreads();
    if (threadIdx.x == 0) {
        float tls = s_l[0] + s_l[1] + s_l[2] + s_l[3];
        float tms = s_m[0] + s_m[1] + s_m[2] + s_m[3];
        out[0] = tls / fmaxf(tms, 1.0f);
    }
}

extern "C" void kernel_launch(void* const* d_in, const int* in_sizes, int n_in,
                              void* d_out, int out_size, void* d_ws, size_t ws_size,
                              hipStream_t stream) {
    const float4* pred = (const float4*)d_in[0];
    const float4* tgt  = (const float4*)d_in[1];
    const int4*   mask = (const int4*)d_in[2];
    float* out  = (float*)d_out;
    float2* parts = (float2*)d_ws;

    const int B = 64, H = 192, W = 192;
    const int HW = H * W;
    const int total4 = B * HW / 4;        // 589824
    const int threads = 256;
    const int blocks = total4 / threads;  // 2304, exact

    ciou_loss_kernel<<<blocks, threads, 0, stream>>>(pred, tgt, mask, parts,
                                                     HW / 4, W / 4);
    reduce_kernel<<<1, threads, 0, stream>>>(parts, blocks, out);
}

// Round 3
// 105.973 us; speedup vs baseline: 3.0987x; 1.0093x over previous
//
#include <hip/hip_runtime.h>
#include <hip/hip_bf16.h>
#include <math.h>

// Problem constants from the reference: B=64, H=192, W=192, STRIDE=8, EPS=1e-7
#define STRIDE_F 8.0f
#define EPS_F 1e-7f
#define PI_2_F 1.57079632679489662f

// Fast reciprocal: v_rcp_f32, ~1 ulp — far inside the 1.56e-2 tolerance.
__device__ __forceinline__ float frcp(float x) { return __builtin_amdgcn_rcpf(x); }

// atan(w / (h)) for w >= 0, h > 0, branch-free.
// Range-reduce via min/max so the poly argument z = min/max is in [0,1];
// degree-11 odd minimax poly, max err ~1e-5 rad.
__device__ __forceinline__ float fast_atan_ratio(float w, float h)
{
    float num = fminf(w, h);
    float den = fmaxf(w, h);
    float z   = num * frcp(den);
    float z2  = z * z;
    float p = fmaf(z2, -0.0117212f,  0.05265332f);
    p = fmaf(z2, p, -0.11643287f);
    p = fmaf(z2, p,  0.19354346f);
    p = fmaf(z2, p, -0.33262347f);
    p = fmaf(z2, p,  0.99997726f);
    p = z * p;
    return (w > h) ? (PI_2_F - p) : p;
}

__device__ __forceinline__ void ciou_elem(
    float cx, float cy,
    float pl, float pt, float pr, float pb,
    float tl, float tt, float tr, float tb,
    int m_i, float& ls, float& ms)
{
    float px1 = cx - pl * STRIDE_F;
    float py1 = cy - pt * STRIDE_F;
    float px2 = cx + pr * STRIDE_F;
    float py2 = cy + pb * STRIDE_F;
    float tx1 = cx - tl * STRIDE_F;
    float ty1 = cy - tt * STRIDE_F;
    float tx2 = cx + tr * STRIDE_F;
    float ty2 = cy + tb * STRIDE_F;

    float w1 = px2 - px1, h1 = py2 - py1;
    float w2 = tx2 - tx1, h2 = ty2 - ty1;
    float iw = fmaxf(fminf(px2, tx2) - fmaxf(px1, tx1), 0.0f);
    float ih = fmaxf(fminf(py2, ty2) - fmaxf(py1, ty1), 0.0f);
    float inter = iw * ih;
    float uni   = w1 * h1 + w2 * h2 - inter + EPS_F;
    float iou   = inter * frcp(uni);

    float cw = fmaxf(px2, tx2) - fminf(px1, tx1);
    float ch = fmaxf(py2, ty2) - fminf(py1, ty1);
    float c2 = cw * cw + ch * ch + EPS_F;

    float dx = tx1 + tx2 - px1 - px2;
    float dy = ty1 + ty2 - py1 - py2;
    float rho2 = (dx * dx + dy * dy) * 0.25f;

    const float FOUR_OVER_PI2 = 0.40528473456935109f; // 4/pi^2
    // w,h >= 0 here (inputs are non-negative offsets), h2+EPS > 0.
    float dv = fast_atan_ratio(w2, h2 + EPS_F) - fast_atan_ratio(w1, h1 + EPS_F);
    float v  = FOUR_OVER_PI2 * dv * dv;
    float alpha = v * frcp(v - iou + (1.0f + EPS_F));
    float ciou  = iou - rho2 * frcp(c2) - alpha * v;

    float m = (m_i != 0) ? 1.0f : 0.0f;
    ls += (1.0f - ciou) * m;
    ms += m;
}

__global__ __launch_bounds__(256) void ciou_loss_kernel(
    const float4* __restrict__ pred, const float4* __restrict__ tgt,
    const int4* __restrict__ mask, float2* __restrict__ parts,
    int HW4, int W4)
{
    int idx4 = blockIdx.x * blockDim.x + threadIdx.x;
    // exact launch: grid*block == total/4, no bounds check needed
    int bb  = idx4 / HW4;
    int hw4 = idx4 - bb * HW4;
    int h   = hw4 / W4;
    int w4  = hw4 - h * W4;

    float cy = ((float)h + 0.5f) * STRIDE_F;
    float cx0 = ((float)(w4 * 4) + 0.5f) * STRIDE_F;

    size_t base = (size_t)bb * 4 * (size_t)HW4 + (size_t)hw4;
    float4 pl4 = pred[base];
    float4 pt4 = pred[base + (size_t)HW4];
    float4 pr4 = pred[base + 2 * (size_t)HW4];
    float4 pb4 = pred[base + 3 * (size_t)HW4];
    float4 tl4 = tgt[base];
    float4 tt4 = tgt[base + (size_t)HW4];
    float4 tr4 = tgt[base + 2 * (size_t)HW4];
    float4 tb4 = tgt[base + 3 * (size_t)HW4];
    int4   mk4 = mask[idx4];

    float ls = 0.0f, ms = 0.0f;
    ciou_elem(cx0 + 0.0f * STRIDE_F, cy, pl4.x, pt4.x, pr4.x, pb4.x,
              tl4.x, tt4.x, tr4.x, tb4.x, mk4.x, ls, ms);
    ciou_elem(cx0 + 1.0f * STRIDE_F, cy, pl4.y, pt4.y, pr4.y, pb4.y,
              tl4.y, tt4.y, tr4.y, tb4.y, mk4.y, ls, ms);
    ciou_elem(cx0 + 2.0f * STRIDE_F, cy, pl4.z, pt4.z, pr4.z, pb4.z,
              tl4.z, tt4.z, tr4.z, tb4.z, mk4.z, ls, ms);
    ciou_elem(cx0 + 3.0f * STRIDE_F, cy, pl4.w, pt4.w, pr4.w, pb4.w,
              tl4.w, tt4.w, tr4.w, tb4.w, mk4.w, ls, ms);

    // wave-64 reduction
    #pragma unroll
    for (int off = 32; off > 0; off >>= 1) {
        ls += __shfl_down(ls, off, 64);
        ms += __shfl_down(ms, off, 64);
    }
    __shared__ float s_l[4];
    __shared__ float s_m[4];
    int wave = threadIdx.x >> 6;
    int lane = threadIdx.x & 63;
    if (lane == 0) { s_l[wave] = ls; s_m[wave] = ms; }
    __syncthreads();
    if (threadIdx.x == 0) {
        float2 p;
        p.x = s_l[0] + s_l[1] + s_l[2] + s_l[3];
        p.y = s_m[0] + s_m[1] + s_m[2] + s_m[3];
        parts[blockIdx.x] = p;
    }
}

__global__ __launch_bounds__(256) void reduce_kernel(
    const float2* __restrict__ parts, int n, float* __restrict__ out)
{
    float ls = 0.0f, ms = 0.0f;
    for (int i = threadIdx.x; i < n; i += 256) {
        float2 p = parts[i];
        ls += p.x;
        ms += p.y;
    }
    #pragma unroll
    for (int off = 32; off > 0; off >>= 1) {
        ls += __shfl_down(ls, off, 64);
        ms += __shfl_down(ms, off, 64);
    }
    __shared__ float s_l[4];
    __shared__ float s_m[4];
    int wave = threadIdx.x >> 6;
    int lane = threadIdx.x & 63;
    if (lane == 0) { s_l[wave] = ls; s_m[wave] = ms; }
    __syncthreads();
    if (threadIdx.x == 0) {
        float tls = s_l[0] + s_l[1] + s_l[2] + s_l[3];
        float tms = s_m[0] + s_m[1] + s_m[2] + s_m[3];
        out[0] = tls / fmaxf(tms, 1.0f);
    }
}

extern "C" void kernel_launch(void* const* d_in, const int* in_sizes, int n_in,
                              void* d_out, int out_size, void* d_ws, size_t ws_size,
                              hipStream_t stream) {
    const float4* pred = (const float4*)d_in[0];
    const float4* tgt  = (const float4*)d_in[1];
    const int4*   mask = (const int4*)d_in[2];
    float* out  = (float*)d_out;
    float2* parts = (float2*)d_ws;

    const int B = 64, H = 192, W = 192;
    const int HW = H * W;
    const int total4 = B * HW / 4;        // 589824
    const int threads = 256;
    const int blocks = total4 / threads;  // 2304, exact

    ciou_loss_kernel<<<blocks, threads, 0, stream>>>(pred, tgt, mask, parts,
                                                     HW / 4, W / 4);
    reduce_kernel<<<1, threads, 0, stream>>>(parts, blocks, out);
}